// Round 7
// baseline (7377.656 us; speedup 1.0000x reference)
//
#include <hip/hip_runtime.h>

#define IN_DIM   512
#define H_DIM    1024
#define OUT_DIM  256
#define B_DIM    64
#define S_DIM    256
#define EPS_F    1e-8f

#define BPG      8      // batches per group
#define NTHREADS 512
#define NWG      256    // one WG per CU (forced by LDS pad)
#define SLOT_STRIDE 65536   // u32 elements per exchange slot

#define OUT_Y_TOTAL ((size_t)B_DIM*S_DIM*OUT_DIM)

typedef float    f32x4 __attribute__((ext_vector_type(4)));
typedef unsigned u32x4 __attribute__((ext_vector_type(4)));
typedef short    s16x8 __attribute__((ext_vector_type(8)));

#define MFMA16 __builtin_amdgcn_mfma_f32_16x16x32_bf16

union B8 { unsigned u[4]; s16x8 v; };

// split f32 -> (bf16 hi, bf16 lo) by truncation; hi+lo reconstructs to ~2^-16 rel.
__device__ __forceinline__ void split_bf16(f32x4 f0, f32x4 f1, s16x8* hi, s16x8* lo) {
  B8 H, L;
  float fv[8];
#pragma unroll
  for (int e = 0; e < 4; ++e) { fv[e] = f0[e]; fv[e+4] = f1[e]; }
#pragma unroll
  for (int d = 0; d < 4; ++d) {
    unsigned u0 = __float_as_uint(fv[2*d]);
    unsigned u1 = __float_as_uint(fv[2*d+1]);
    unsigned t0 = u0 & 0xffff0000u, t1 = u1 & 0xffff0000u;
    H.u[d] = (u0 >> 16) | t1;
    L.u[d] = ((__float_as_uint(fv[2*d]   - __uint_as_float(t0))) >> 16)
           | ((__float_as_uint(fv[2*d+1] - __uint_as_float(t1))) & 0xffff0000u);
  }
  *hi = H.v; *lo = L.v;
}

// exchange word: [hi bf16 | lo bf16]; 12-bit phase tag, 3 bits per word's lo
// (tags unique across all 1537 phases -> stale lines can never false-match
//  within a launch; cross-replay matches are value-identical by determinism)
__device__ __forceinline__ u32x4 enc_h(f32x4 hn, unsigned tag) {
  u32x4 e;
#pragma unroll
  for (int k = 0; k < 4; ++k) {
    unsigned uh = __float_as_uint(hn[k]) & 0xFFFF0000u;
    float r = hn[k] - __uint_as_float(uh);
    e[k] = (uh | (__float_as_uint(r) >> 16)) & ~7u;
  }
  e.x |= tag & 7u; e.y |= (tag >> 3) & 7u; e.z |= (tag >> 6) & 7u; e.w |= (tag >> 9) & 7u;
  return e;
}
__device__ __forceinline__ unsigned dec_tag(u32x4 q) {
  return (q.x & 7u) | ((q.y & 7u) << 3) | ((q.z & 7u) << 6) | ((q.w & 7u) << 9);
}

__device__ __forceinline__ s16x8 pack_hi(u32x4 a, u32x4 b) {
  B8 t;
  t.u[0] = (a.y & 0xFFFF0000u) | (a.x >> 16);
  t.u[1] = (a.w & 0xFFFF0000u) | (a.z >> 16);
  t.u[2] = (b.y & 0xFFFF0000u) | (b.x >> 16);
  t.u[3] = (b.w & 0xFFFF0000u) | (b.z >> 16);
  return t.v;
}
__device__ __forceinline__ s16x8 pack_lo(u32x4 a, u32x4 b) {
  B8 t;   // strip 3 stolen tag bits from every word's residual
  t.u[0] = ((a.y & 0xFFF8u) << 16) | (a.x & 0xFFF8u);
  t.u[1] = ((a.w & 0xFFF8u) << 16) | (a.z & 0xFFF8u);
  t.u[2] = ((b.y & 0xFFF8u) << 16) | (b.x & 0xFFF8u);
  t.u[3] = ((b.w & 0xFFF8u) << 16) | (b.z & 0xFFF8u);
  return t.v;
}

#define POLL_BODY(FLAGS)                                                      \
  asm volatile(                                                               \
    "global_load_dwordx4 %0, %8, off " FLAGS "\n\t"                           \
    "global_load_dwordx4 %1, %8, off offset:16 " FLAGS "\n\t"                 \
    "global_load_dwordx4 %2, %8, off offset:128 " FLAGS "\n\t"                \
    "global_load_dwordx4 %3, %8, off offset:144 " FLAGS "\n\t"                \
    "global_load_dwordx4 %4, %8, off offset:256 " FLAGS "\n\t"                \
    "global_load_dwordx4 %5, %8, off offset:272 " FLAGS "\n\t"                \
    "global_load_dwordx4 %6, %8, off offset:384 " FLAGS "\n\t"                \
    "global_load_dwordx4 %7, %8, off offset:400 " FLAGS "\n\t"                \
    "s_waitcnt vmcnt(0)"                                                      \
    : "=&v"(q0), "=&v"(q1), "=&v"(q2), "=&v"(q3),                             \
      "=&v"(q4), "=&v"(q5), "=&v"(q6), "=&v"(q7)                              \
    : "v"(ap) : "memory")

__global__ void __launch_bounds__(NTHREADS)
ltc_kernel(const float* __restrict__ x, const float* __restrict__ h0,
           const float* __restrict__ tspan, const float* __restrict__ tau,
           const float* __restrict__ Wiw, const float* __restrict__ Wib,
           const float* __restrict__ Wrw, const float* __restrict__ wmask,
           const float* __restrict__ Wow, const float* __restrict__ Wob,
           const float* __restrict__ alpha_p, const float* __restrict__ beta_p,
           const float* __restrict__ mu_p, const float* __restrict__ sigma_p,
           float* __restrict__ out, unsigned* __restrict__ hb)
{
  __shared__ __align__(16) float sch[2][8][8][36];  // [slot][kp][b][j] h partials
  __shared__ __align__(16) float scx[8][8][36];     // iin partials
  __shared__ __align__(16) float scy[8][8][9];      // y partials
  __shared__ char lds_pad[57344];   // force 1 WG/CU: all 256 CUs used ->
                                    // blockIdx%8 ~= physical XCD (perf only)

  const int tid = threadIdx.x;
  ((volatile char*)lds_pad)[tid] = 0;   // keep pad allocated

  const int wg  = blockIdx.x;
  const int g   = wg & 7;           // group (XCD heuristic; correctness-independent)
  const int w   = wg >> 3;          // 0..31 within group
  const int b0g = g * BPG;
  const int jw0 = w * 32;
  const int l   = tid & 63;
  const int v   = tid >> 6;         // wave id: K-part (consumer), batch owner (producer)
  const int gb_v = b0g + v;
  const int le  = l & 7;
  const int j4  = jw0 + 4*le;

  // ---- W_rec B-frags (masked, split bf16) -> registers, permanent
  s16x8 wbh[4][2], wbl[4][2];
#pragma unroll
  for (int i = 0; i < 4; ++i) {
    const int k0 = v*128 + i*32 + ((l >> 4) << 3);
#pragma unroll
    for (int nt = 0; nt < 2; ++nt) {
      const size_t go = (size_t)(jw0 + nt*16 + (l & 15))*H_DIM + k0;
      f32x4 w0 = *(const f32x4*)(Wrw + go)     * *(const f32x4*)(wmask + go);
      f32x4 w1 = *(const f32x4*)(Wrw + go + 4) * *(const f32x4*)(wmask + go + 4);
      split_bf16(w0, w1, &wbh[i][nt], &wbl[i][nt]);
    }
  }

  // ---- per-lane (lanes 0..7) epilogue state for batch b=v
  f32x4 mu4  = *(const f32x4*)(mu_p + j4);
  f32x4 sg4  = *(const f32x4*)(sigma_p + j4);
  f32x4 al4  = *(const f32x4*)(alpha_p + j4);
  f32x4 be4  = *(const f32x4*)(beta_p + j4);
  f32x4 ta4  = *(const f32x4*)(tau + j4);
  f32x4 wib4 = *(const f32x4*)(Wib + j4);
  f32x4 sgi4, ti4;
#pragma unroll
  for (int e = 0; e < 4; ++e) { sgi4[e] = 1.0f/(sg4[e]+EPS_F); ti4[e] = 1.0f/ta4[e]; }
  const float wob_s = Wob[w*8 + le];
  f32x4 hold4 = *(const f32x4*)(h0 + ((size_t)gb_v << 10) + j4);
  float tsc = tspan[(size_t)gb_v*S_DIM] * (1.0f/6.0f);

  // ---- publish h: local L2 copy (sc0) + authoritative MALL copy (sc0 sc1).
  // Same value -> any writeback interleaving is benign.
  auto publish = [&](f32x4 hn, unsigned slot, unsigned tag) {
    u32x4 enc = enc_h(hn, tag);
    unsigned* dst = hb + slot*SLOT_STRIDE + ((unsigned)gb_v << 10) + j4;
    asm volatile("global_store_dwordx4 %0, %1, off sc0\n\t"
                 "global_store_dwordx4 %0, %1, off sc0 sc1"
                 :: "v"(dst), "v"(enc) : "memory");
  };

  // ---- phase 0: publish tagged h0 (slot 0, tag 0)
  if (l < 8) publish(hold4, 0u, 0u);

  // ---- iin partial MFMA for time tt (x and Win plain cached loads)
  auto iin_partials = [&](int tt, f32x4& ax0, f32x4& ax1) {
    const int bL = l & 7, ko = (l >> 4) << 3;
    const float* xp = x + ((size_t)(b0g + bL)*S_DIM + tt)*IN_DIM + v*64 + ko;
    f32x4 xq0 = *(const f32x4*)xp,        xq1 = *(const f32x4*)(xp + 4);
    f32x4 xq2 = *(const f32x4*)(xp + 32), xq3 = *(const f32x4*)(xp + 36);
    const int jn0 = jw0 + (l & 15);
#pragma unroll
    for (int i2 = 0; i2 < 2; ++i2) {
      s16x8 xh, xl;
      split_bf16(i2 ? xq2 : xq0, i2 ? xq3 : xq1, &xh, &xl);
#pragma unroll
      for (int nt = 0; nt < 2; ++nt) {
        const float* wp = Wiw + (size_t)(jn0 + nt*16)*IN_DIM + v*64 + i2*32 + ko;
        s16x8 wh, wl;
        split_bf16(*(const f32x4*)wp, *(const f32x4*)(wp + 4), &wh, &wl);
        if (nt == 0) {
          ax0 = MFMA16(xh, wh, ax0, 0,0,0);
          ax0 = MFMA16(xl, wh, ax0, 0,0,0);
          ax0 = MFMA16(xh, wl, ax0, 0,0,0);
        } else {
          ax1 = MFMA16(xh, wh, ax1, 0,0,0);
          ax1 = MFMA16(xl, wh, ax1, 0,0,0);
          ax1 = MFMA16(xh, wl, ax1, 0,0,0);
        }
      }
    }
  };

  // ---- Wout B-frags on demand (cached loads; doY phases only)
  auto load_wout = [&](s16x8 woY[4], s16x8 wlY[4]) {
    B8 z; z.u[0] = z.u[1] = z.u[2] = z.u[3] = 0;
#pragma unroll
    for (int i = 0; i < 4; ++i) { woY[i] = z.v; wlY[i] = z.v; }
    if ((l & 15) < 8) {
#pragma unroll
      for (int i = 0; i < 4; ++i) {
        const int k0 = v*128 + i*32 + ((l >> 4) << 3);
        const size_t go = (size_t)(w*8 + (l & 15))*H_DIM + k0;
        split_bf16(*(const f32x4*)(Wow + go), *(const f32x4*)(Wow + go + 4),
                   &woY[i], &wlY[i]);
      }
    }
  };

  // ---- consumer poll: even attempts = local L2 (sc0), odd = MALL (sc0 sc1).
  // Mis-placed pairs always make progress via the authoritative attempts.
  auto poll_frag = [&](unsigned slotC, unsigned tagC,
                       u32x4& q0, u32x4& q1, u32x4& q2, u32x4& q3,
                       u32x4& q4, u32x4& q5, u32x4& q6, u32x4& q7) {
    const unsigned* ap = hb + slotC*SLOT_STRIDE
                       + ((unsigned)(b0g + (l & 7)) << 10)
                       + (unsigned)(v*128 + ((l >> 4) << 3));
    for (unsigned attempt = 0;; ++attempt) {
      int ok;
      if ((l & 15) < 8) {
        if (attempt & 1) { POLL_BODY("sc0 sc1"); }
        else             { POLL_BODY("sc0"); }
        ok = (dec_tag(q0) == tagC) & (dec_tag(q1) == tagC) &
             (dec_tag(q2) == tagC) & (dec_tag(q3) == tagC) &
             (dec_tag(q4) == tagC) & (dec_tag(q5) == tagC) &
             (dec_tag(q6) == tagC) & (dec_tag(q7) == tagC);
      } else ok = 1;
      if (__all(ok)) break;
      __builtin_amdgcn_s_sleep(1);
    }
  };

  // ---- pre-loop: iin(0) -> registers
  f32x4 iin4 = {0.f,0.f,0.f,0.f}, iin_nx = {0.f,0.f,0.f,0.f};
  {
    f32x4 ax0 = {0.f,0.f,0.f,0.f}, ax1 = {0.f,0.f,0.f,0.f};
    iin_partials(0, ax0, ax1);
    if (l < 32) {
      const int brow = (l >> 4) * 4, l15 = l & 15;
      float* scxp = &scx[v][brow][l15];
#pragma unroll
      for (int qq = 0; qq < 4; ++qq) { scxp[qq*36] = ax0[qq]; scxp[qq*36 + 16] = ax1[qq]; }
    }
    __syncthreads();
    if (l < 8) {
      f32x4 s = wib4;
#pragma unroll
      for (int k2 = 0; k2 < 8; ++k2) s += *(const f32x4*)&scx[k2][v][4*le];
      iin4 = s;
    }
    __syncthreads();
  }

  unsigned p = 1;
#pragma unroll 1
  for (int t = 0; t < S_DIM; ++t) {
#pragma unroll 1
    for (int u = 0; u < 6; ++u, ++p) {
      const unsigned slotC = (p-1) & 1, tagC = (p-1) & 0xFFFu;
      const unsigned slotP = p & 1,     tagP = p & 0xFFFu;
      const bool doY = (u == 0);
      const bool doX = (u == 3) && (t + 1 < S_DIM);

      s16x8 woY[4], wlY[4];
      if (doY) load_wout(woY, wlY);    // cached loads; overlap the poll below

      u32x4 q0,q1,q2,q3,q4,q5,q6,q7;
      poll_frag(slotC, tagC, q0,q1,q2,q3,q4,q5,q6,q7);

      // ---- MFMA: 3-split bf16 (hh + lh + hl), B from registers
      f32x4 acc0 = {0.f,0.f,0.f,0.f}, acc1 = {0.f,0.f,0.f,0.f};
      f32x4 accy = {0.f,0.f,0.f,0.f};
#pragma unroll
      for (int i = 0; i < 4; ++i) {
        u32x4 qa = (i==0) ? q0 : (i==1) ? q2 : (i==2) ? q4 : q6;
        u32x4 qb = (i==0) ? q1 : (i==1) ? q3 : (i==2) ? q5 : q7;
        s16x8 ah = pack_hi(qa, qb), al = pack_lo(qa, qb);
        acc0 = MFMA16(ah, wbh[i][0], acc0, 0,0,0);
        acc0 = MFMA16(al, wbh[i][0], acc0, 0,0,0);
        acc0 = MFMA16(ah, wbl[i][0], acc0, 0,0,0);
        acc1 = MFMA16(ah, wbh[i][1], acc1, 0,0,0);
        acc1 = MFMA16(al, wbh[i][1], acc1, 0,0,0);
        acc1 = MFMA16(ah, wbl[i][1], acc1, 0,0,0);
        if (doY) {
          accy = MFMA16(ah, woY[i], accy, 0,0,0);
          accy = MFMA16(al, woY[i], accy, 0,0,0);
          accy = MFMA16(ah, wlY[i], accy, 0,0,0);
        }
      }
      f32x4 ax0 = {0.f,0.f,0.f,0.f}, ax1 = {0.f,0.f,0.f,0.f};
      if (doX) iin_partials(t + 1, ax0, ax1);

      // ---- partials -> LDS scratch
      if (l < 32) {
        const int brow = (l >> 4) * 4, l15 = l & 15;
        float* schp = &sch[slotP][v][brow][l15];
#pragma unroll
        for (int qq = 0; qq < 4; ++qq) { schp[qq*36] = acc0[qq]; schp[qq*36 + 16] = acc1[qq]; }
        if (doX) {
          float* scxp = &scx[v][brow][l15];
#pragma unroll
          for (int qq = 0; qq < 4; ++qq) { scxp[qq*36] = ax0[qq]; scxp[qq*36 + 16] = ax1[qq]; }
        }
        if (doY && l15 < 8) {
          float* scyp = &scy[v][brow][l15];
#pragma unroll
          for (int qq = 0; qq < 4; ++qq) scyp[qq*9] = accy[qq];
        }
      }
      __syncthreads();

      // ---- distributed epilogue: wave v owns batch b=v (lanes 0..7)
      if (l < 8) {
        f32x4 ir = {0.f,0.f,0.f,0.f};
#pragma unroll
        for (int k2 = 0; k2 < 8; ++k2) ir += *(const f32x4*)&sch[slotP][k2][v][4*le];
        f32x4 hn;
#pragma unroll
        for (int e = 0; e < 4; ++e) {
          const float z  = (ir[e] - mu4[e]) * sgi4[e];
          const float f  = 1.0f / (1.0f + __expf(-z));
          const float dh = -al4[e]*hold4[e] + be4[e]*f*(iin4[e] + ir[e]);
          hn[e] = hold4[e] + tsc*dh*ti4[e];
        }
        hold4 = hn;
        publish(hn, slotP, tagP);
        if (doY && t > 0) {
          float s = wob_s;
#pragma unroll
          for (int k2 = 0; k2 < 8; ++k2) s += scy[k2][v][le];
          out[((size_t)gb_v*S_DIM + (t-1))*OUT_DIM + w*8 + le] = s;
        }
        if (doX) {
          f32x4 s = wib4;
#pragma unroll
          for (int k2 = 0; k2 < 8; ++k2) s += *(const f32x4*)&scx[k2][v][4*le];
          iin_nx = s;
        }
        if (u == 5) {
          if (t + 1 < S_DIM) {
            tsc = tspan[(size_t)gb_v*S_DIM + t + 1] * (1.0f/6.0f);
            iin4 = iin_nx;
          } else {
            *(f32x4*)(out + OUT_Y_TOTAL + ((size_t)gb_v << 10) + j4) = hn;
          }
        }
      }
    }
  }

  // ---- tail: y(S-1) from final h (phase 1536)
  {
    const unsigned slotC = (p-1) & 1, tagC = (p-1) & 0xFFFu;
    s16x8 woY[4], wlY[4];
    load_wout(woY, wlY);
    u32x4 q0,q1,q2,q3,q4,q5,q6,q7;
    poll_frag(slotC, tagC, q0,q1,q2,q3,q4,q5,q6,q7);
    f32x4 accy = {0.f,0.f,0.f,0.f};
#pragma unroll
    for (int i = 0; i < 4; ++i) {
      u32x4 qa = (i==0) ? q0 : (i==1) ? q2 : (i==2) ? q4 : q6;
      u32x4 qb = (i==0) ? q1 : (i==1) ? q3 : (i==2) ? q5 : q7;
      s16x8 ah = pack_hi(qa, qb), al = pack_lo(qa, qb);
      accy = MFMA16(ah, woY[i], accy, 0,0,0);
      accy = MFMA16(al, woY[i], accy, 0,0,0);
      accy = MFMA16(ah, wlY[i], accy, 0,0,0);
    }
    if (l < 32 && (l & 15) < 8) {
      const int brow = (l >> 4) * 4, l15 = l & 15;
      float* scyp = &scy[v][brow][l15];
#pragma unroll
      for (int qq = 0; qq < 4; ++qq) scyp[qq*9] = accy[qq];
    }
    __syncthreads();
    if (l < 8) {
      float s = wob_s;
#pragma unroll
      for (int k2 = 0; k2 < 8; ++k2) s += scy[k2][v][le];
      out[((size_t)gb_v*S_DIM + (S_DIM-1))*OUT_DIM + w*8 + le] = s;
    }
  }
}

extern "C" void kernel_launch(void* const* d_in, const int* in_sizes, int n_in,
                              void* d_out, int out_size, void* d_ws, size_t ws_size,
                              hipStream_t stream) {
  const float* x    = (const float*)d_in[0];
  const float* h0   = (const float*)d_in[1];
  const float* ts   = (const float*)d_in[2];
  const float* tau  = (const float*)d_in[3];
  const float* Wiw  = (const float*)d_in[4];
  const float* Wib  = (const float*)d_in[5];
  const float* Wrw  = (const float*)d_in[6];
  const float* msk  = (const float*)d_in[7];
  const float* Wow  = (const float*)d_in[8];
  const float* Wob  = (const float*)d_in[9];
  const float* alp  = (const float*)d_in[10];
  const float* bet  = (const float*)d_in[11];
  const float* mu   = (const float*)d_in[12];
  const float* sg   = (const float*)d_in[13];
  float* out = (float*)d_out;
  unsigned* hb = (unsigned*)d_ws;   // 2 slots x 256KB tagged h exchange

  // poison tags: 0xFF... decodes to tag 4095 > max phase 1537 -> never matches
  hipMemsetAsync(hb, 0xFF, 2*SLOT_STRIDE*sizeof(unsigned), stream);

  void* args[] = { (void*)&x, (void*)&h0, (void*)&ts, (void*)&tau,
                   (void*)&Wiw, (void*)&Wib, (void*)&Wrw, (void*)&msk,
                   (void*)&Wow, (void*)&Wob, (void*)&alp, (void*)&bet,
                   (void*)&mu, (void*)&sg, (void*)&out, (void*)&hb };
  hipLaunchCooperativeKernel((const void*)ltc_kernel, dim3(NWG), dim3(NTHREADS),
                             args, 0, stream);
}